// Round 2
// baseline (501.875 us; speedup 1.0000x reference)
//
#include <hip/hip_runtime.h>
#include <math.h>

#define S_LEN 8192
#define BATCH 32
#define HDIM 256
#define DDIM 256
#define TS 32           // s-rows per block in att kernel (32 -> 4 blocks/CU)
#define LDK 264         // padded LDS row stride (bf16 elems): 528B rows -> 2-way bank aliasing (free)

typedef float f32x4 __attribute__((ext_vector_type(4)));
typedef short s16x8 __attribute__((ext_vector_type(8)));
typedef short s16x4 __attribute__((ext_vector_type(4)));

static __device__ __forceinline__ unsigned short bf16_rne(float f) {
    unsigned u = __float_as_uint(f);
    u += 0x7FFFu + ((u >> 16) & 1u);
    return (unsigned short)(u >> 16);
}
static __device__ __forceinline__ float bf16_f32(unsigned short h) {
    return __uint_as_float(((unsigned)h) << 16);
}
static __device__ __forceinline__ float fast_tanh(float x) {
    // 1 - 2/(exp(2x)+1); monotone, NaN-free, saturates correctly at +-inf
    float e = __expf(2.0f * x);
    return 1.0f - 2.0f / (e + 1.0f);
}

// ---------------------------------------------------------------------------
// Kernel 0: blocks [0,32): cin[b][h] = x[b]·W_in[h] + b_in[h] + b_ctx[h]
//   coalesced: each wave owns 64 h-rows; lanes split d; shfl_xor reduce.
//           blocks [32,64): W_ctx -> bf16 hi/lo, pre-swizzled into MFMA
//           B-fragment order: Wf[((nt*8+ks)*64 + lane)*8 + j] =
//              W_ctx[h = nt*16 + (lane&15)][d = ks*32 + (lane>>4)*8 + j]
// ---------------------------------------------------------------------------
__global__ void prep_kernel(const float* __restrict__ x,
                            const float* __restrict__ W_in,
                            const float* __restrict__ b_in,
                            const float* __restrict__ W_ctx,
                            const float* __restrict__ b_ctx,
                            float* __restrict__ cin,
                            unsigned short* __restrict__ Wf_hi,
                            unsigned short* __restrict__ Wf_lo) {
    const int bx = blockIdx.x;
    const int t  = threadIdx.x;
    if (bx < BATCH) {
        const int b = bx;
        const int w = t >> 6;           // wave 0..3 -> h block [w*64, w*64+64)
        const int l = t & 63;
        // lane l holds x[b][l + 64j]
        float xv[4];
        #pragma unroll
        for (int j = 0; j < 4; ++j) xv[j] = x[b * DDIM + l + 64 * j];
        #pragma unroll 4
        for (int hh = 0; hh < 64; ++hh) {
            const int h = w * 64 + hh;
            const float* wr = W_in + h * DDIM;      // coalesced: lanes read wr[l+64j]
            float acc = 0.f;
            #pragma unroll
            for (int j = 0; j < 4; ++j) acc += xv[j] * wr[l + 64 * j];
            acc += __shfl_xor(acc, 1);
            acc += __shfl_xor(acc, 2);
            acc += __shfl_xor(acc, 4);
            acc += __shfl_xor(acc, 8);
            acc += __shfl_xor(acc, 16);
            acc += __shfl_xor(acc, 32);
            if (l == (h & 63)) cin[b * HDIM + h] = acc + b_in[h] + b_ctx[h];
        }
    } else {
        const int g  = (bx - BATCH) * 256 + t;   // 0..8191 fragment-groups
        const int nt = g >> 9;
        const int ks = (g >> 6) & 7;
        const int l  = g & 63;
        const int h  = nt * 16 + (l & 15);
        const int d0 = ks * 32 + (l >> 4) * 8;
        const float* src = W_ctx + h * DDIM + d0;
        s16x8 vh, vl;
        #pragma unroll
        for (int j = 0; j < 8; ++j) {
            float f = src[j];
            unsigned short hb = bf16_rne(f);
            vh[j] = (short)hb;
            vl[j] = (short)bf16_rne(f - bf16_f32(hb));
        }
        *(s16x8*)(Wf_hi + (size_t)g * 8) = vh;
        *(s16x8*)(Wf_lo + (size_t)g * 8) = vl;
    }
}

// ---------------------------------------------------------------------------
// Kernel 1: per (s-tile, b) block: ctx GEMM via 3-pass split-bf16 MFMA,
// fused tanh/V-dot epilogue -> att[b][s]; also emits mask floats.
// TS=32 -> LDS ~36 KB -> 4 blocks/CU (16 waves/CU).
// ---------------------------------------------------------------------------
__launch_bounds__(256, 4)
__global__ void att_kernel(const float* __restrict__ context,
                           const int* __restrict__ mask,
                           const float* __restrict__ cin,
                           const float* __restrict__ V,
                           const unsigned short* __restrict__ Wf_hi,
                           const unsigned short* __restrict__ Wf_lo,
                           float* __restrict__ att,
                           float* __restrict__ out_mask) {
    __shared__ unsigned short a_hi[TS * LDK];   // 16896 B
    __shared__ unsigned short a_lo[TS * LDK];   // 16896 B
    __shared__ float cin_s[HDIM];
    __shared__ float v_s[HDIM];
    __shared__ float att_part[4][TS];

    const int sblk = blockIdx.x;     // 0..255
    const int b    = blockIdx.y;     // 0..31
    const int t    = threadIdx.x;
    const int w    = t >> 6;         // wave 0..3
    const int l    = t & 63;
    const int lane16 = l & 15;
    const int q      = l >> 4;

    cin_s[t] = cin[b * HDIM + t];
    v_s[t]   = V[t];

    // ---- stage context tile [TS][DDIM] fp32 -> bf16 hi/lo in LDS ----
    const float* cbase = context + ((size_t)b * S_LEN + (size_t)sblk * TS) * DDIM;
    #pragma unroll
    for (int i = 0; i < 8; ++i) {
        int f   = i * 256 + t;       // float4 index 0..2047
        int row = f >> 6;            // 64 float4 per row
        int c4  = f & 63;
        f32x4 v = *(const f32x4*)(cbase + row * DDIM + c4 * 4);
        s16x4 hi, lo;
        #pragma unroll
        for (int j = 0; j < 4; ++j) {
            unsigned short hb = bf16_rne(v[j]);
            hi[j] = (short)hb;
            lo[j] = (short)bf16_rne(v[j] - bf16_f32(hb));
        }
        *(s16x4*)(a_hi + row * LDK + c4 * 4) = hi;
        *(s16x4*)(a_lo + row * LDK + c4 * 4) = lo;
    }
    __syncthreads();

    // ---- 3-pass split-bf16 MFMA: acc += Ah*Bh + Ah*Bl + Al*Bh ----
    f32x4 acc[2][4];   // [m-tile][n-tile within wave's group]
    #pragma unroll
    for (int mt = 0; mt < 2; ++mt)
        #pragma unroll
        for (int i = 0; i < 4; ++i) acc[mt][i] = (f32x4){0.f, 0.f, 0.f, 0.f};

    const int ntb = w * 4;           // wave's 4 n-tiles: distinct per wave
    #pragma unroll
    for (int ks = 0; ks < 8; ++ks) {
        s16x8 bh[4], bl[4];
        #pragma unroll
        for (int i = 0; i < 4; ++i) {
            size_t off = ((size_t)((ntb + i) * 8 + ks) * 64 + l) * 8;
            bh[i] = *(const s16x8*)(Wf_hi + off);   // coalesced 16B/lane, L2-hot
            bl[i] = *(const s16x8*)(Wf_lo + off);
        }
        s16x8 ah[2], al[2];
        #pragma unroll
        for (int mt = 0; mt < 2; ++mt) {
            int o = (mt * 16 + lane16) * LDK + ks * 32 + q * 8;
            ah[mt] = *(const s16x8*)(a_hi + o);     // ds_read_b128
            al[mt] = *(const s16x8*)(a_lo + o);
        }
        #pragma unroll
        for (int mt = 0; mt < 2; ++mt)
            #pragma unroll
            for (int i = 0; i < 4; ++i) {
                acc[mt][i] = __builtin_amdgcn_mfma_f32_16x16x32_bf16(ah[mt], bh[i], acc[mt][i], 0, 0, 0);
                acc[mt][i] = __builtin_amdgcn_mfma_f32_16x16x32_bf16(ah[mt], bl[i], acc[mt][i], 0, 0, 0);
                acc[mt][i] = __builtin_amdgcn_mfma_f32_16x16x32_bf16(al[mt], bh[i], acc[mt][i], 0, 0, 0);
            }
    }

    // ---- epilogue: tanh(ctx + cin) * V, reduce over h ----
    // C/D layout: col h' = lane&15 (within n-tile), row s' = quad*4 + reg
    float part[2][4] = {};   // [mt][reg]
    #pragma unroll
    for (int i = 0; i < 4; ++i) {
        int h = (ntb + i) * 16 + lane16;
        float c  = cin_s[h];
        float vv = v_s[h];
        #pragma unroll
        for (int mt = 0; mt < 2; ++mt)
            #pragma unroll
            for (int r = 0; r < 4; ++r)
                part[mt][r] += fast_tanh(acc[mt][i][r] + c) * vv;
    }
    // sum the 16 h-columns within each quad (xor 1,2,4,8 stays inside 16 lanes)
    #pragma unroll
    for (int mt = 0; mt < 2; ++mt)
        #pragma unroll
        for (int r = 0; r < 4; ++r) {
            float v = part[mt][r];
            v += __shfl_xor(v, 1);
            v += __shfl_xor(v, 2);
            v += __shfl_xor(v, 4);
            v += __shfl_xor(v, 8);
            part[mt][r] = v;
        }
    if (lane16 == 0) {
        #pragma unroll
        for (int mt = 0; mt < 2; ++mt)
            #pragma unroll
            for (int r = 0; r < 4; ++r)
                att_part[w][mt * 16 + q * 4 + r] = part[mt][r];
    }
    __syncthreads();

    if (t < TS) {
        float a = att_part[0][t] + att_part[1][t] + att_part[2][t] + att_part[3][t];
        a = 10.0f * fast_tanh(a);
        int s  = sblk * TS + t;
        int mk = mask[b * S_LEN + s];
        att[(size_t)b * S_LEN + s] = mk ? a : -INFINITY;
        out_mask[(size_t)b * S_LEN + s] = mk ? 1.0f : 0.0f;
    }
}

// ---------------------------------------------------------------------------
// Kernel 2: per-b argmax (first-index ties, like jnp.argmax) + p = 1/sum(exp)
// out layout: [0,32) indices as float, [32,64) p, [64,...) mask (written above)
// ---------------------------------------------------------------------------
__global__ void reduce_kernel(const float* __restrict__ att,
                              float* __restrict__ out) {
    __shared__ float smax[256];
    __shared__ int   sidx[256];
    const int b = blockIdx.x;
    const int t = threadIdx.x;
    const float* row = att + (size_t)b * S_LEN;

    float best = -INFINITY;
    int   bid  = 0x7fffffff;
    for (int s = t; s < S_LEN; s += 256) {
        float v = row[s];
        if (v > best) { best = v; bid = s; }   // ascending s -> first index within thread
    }
    smax[t] = best; sidx[t] = bid;
    __syncthreads();
    for (int off = 128; off > 0; off >>= 1) {
        if (t < off) {
            float ov = smax[t + off]; int oi = sidx[t + off];
            if (ov > smax[t] || (ov == smax[t] && oi < sidx[t])) { smax[t] = ov; sidx[t] = oi; }
        }
        __syncthreads();
    }
    const float mx = smax[0];
    const int   ix = sidx[0];
    __syncthreads();

    float sum = 0.f;
    for (int s = t; s < S_LEN; s += 256)
        sum += __expf(row[s] - mx);            // masked -inf -> exp -> 0
    smax[t] = sum;
    __syncthreads();
    for (int off = 128; off > 0; off >>= 1) {
        if (t < off) smax[t] += smax[t + off];
        __syncthreads();
    }
    if (t == 0) {
        out[b]         = (float)ix;
        out[BATCH + b] = 1.0f / smax[0];
    }
}

// ---------------------------------------------------------------------------
extern "C" void kernel_launch(void* const* d_in, const int* in_sizes, int n_in,
                              void* d_out, int out_size, void* d_ws, size_t ws_size,
                              hipStream_t stream) {
    const float* x       = (const float*)d_in[0];
    const float* context = (const float*)d_in[1];
    const int*   mask    = (const int*)d_in[2];
    const float* W_in    = (const float*)d_in[3];
    const float* b_in    = (const float*)d_in[4];
    const float* W_ctx   = (const float*)d_in[5];
    const float* b_ctx   = (const float*)d_in[6];
    const float* V       = (const float*)d_in[7];
    float* out = (float*)d_out;

    char* ws = (char*)d_ws;
    float*          cin   = (float*)ws;                                  // 32 KB
    unsigned short* Wf_hi = (unsigned short*)(ws + 32 * 1024);           // 128 KB
    unsigned short* Wf_lo = (unsigned short*)(ws + 160 * 1024);          // 128 KB
    float*          att   = (float*)(ws + 288 * 1024);                   // 1 MB

    float* out_mask = out + 64;

    prep_kernel<<<64, 256, 0, stream>>>(x, W_in, b_in, W_ctx, b_ctx, cin, Wf_hi, Wf_lo);
    dim3 grid(S_LEN / TS, BATCH);
    att_kernel<<<grid, 256, 0, stream>>>(context, mask, cin, V, Wf_hi, Wf_lo, att, out_mask);
    reduce_kernel<<<BATCH, 256, 0, stream>>>(att, out);
}

// Round 4
// 434.598 us; speedup vs baseline: 1.1548x; 1.1548x over previous
//
#include <hip/hip_runtime.h>
#include <math.h>

#define S_LEN 8192
#define BATCH 32
#define HDIM 256
#define DDIM 256
#define TS 32           // s-rows per block in att kernel
#define LDK 264         // padded LDS row stride (halfs): 528 B rows, odd*16B -> conflict-free b128 reads

typedef float f32x4 __attribute__((ext_vector_type(4)));
typedef __fp16 h16x2 __attribute__((ext_vector_type(2)));
typedef __fp16 h16x4 __attribute__((ext_vector_type(4)));
typedef _Float16 f16x4 __attribute__((ext_vector_type(4)));
typedef _Float16 f16x8 __attribute__((ext_vector_type(8)));

static __device__ __forceinline__ float fast_tanh(float x) {
    // 1 - 2/(exp(2x)+1); monotone, NaN-free, saturates correctly at +-inf
    float e = __expf(2.0f * x);
    return 1.0f - 2.0f / (e + 1.0f);
}

// ---------------------------------------------------------------------------
// Kernel 0: blocks [0,32): cin[b][h] = x[b]·W_in[h] + b_in[h] + b_ctx[h]
//           blocks [32,64): W_ctx -> fp16 (RNE), pre-swizzled into MFMA
//           B-fragment order: Wf[((nt*8+ks)*64 + lane)*8 + j] =
//              fp16(W_ctx[h = nt*16 + (lane&15)][d = ks*32 + (lane>>4)*8 + j])
// ---------------------------------------------------------------------------
__global__ void prep_kernel(const float* __restrict__ x,
                            const float* __restrict__ W_in,
                            const float* __restrict__ b_in,
                            const float* __restrict__ W_ctx,
                            const float* __restrict__ b_ctx,
                            float* __restrict__ cin,
                            _Float16* __restrict__ Wf) {
    __shared__ float xs[DDIM];
    const int bx = blockIdx.x;
    const int t  = threadIdx.x;
    if (bx < BATCH) {
        xs[t] = x[bx * DDIM + t];
        __syncthreads();
        const float* wr = W_in + t * DDIM;   // thread t owns output h = t
        float acc = b_in[t] + b_ctx[t];
        #pragma unroll 8
        for (int d = 0; d < DDIM; ++d) acc += xs[d] * wr[d];
        cin[bx * HDIM + t] = acc;
    } else {
        const int g  = (bx - BATCH) * 256 + t;   // 0..8191 fragment-groups
        const int nt = g >> 9;
        const int ks = (g >> 6) & 7;
        const int l  = g & 63;
        const int h  = nt * 16 + (l & 15);
        const int d0 = ks * 32 + (l >> 4) * 8;
        const float* src = W_ctx + h * DDIM + d0;
        f16x8 vh;
        #pragma unroll
        for (int j = 0; j < 8; ++j) vh[j] = (_Float16)src[j];   // v_cvt_f16_f32, RNE
        *(f16x8*)(Wf + (size_t)g * 8) = vh;
    }
}

// ---------------------------------------------------------------------------
// Kernel 1: per (s-tile, b) block: ctx GEMM via 2-pass split-fp16 MFMA
//   (A split hi/lo, W single fp16: exact A·fp16(W) to ~2^-22),
// fused tanh/V-dot epilogue -> att[b][s]; also emits mask floats.
// ---------------------------------------------------------------------------
__launch_bounds__(256, 4)
__global__ void att_kernel(const float* __restrict__ context,
                           const int* __restrict__ mask,
                           const float* __restrict__ cin,
                           const float* __restrict__ V,
                           const _Float16* __restrict__ Wf,
                           float* __restrict__ att,
                           float* __restrict__ out_mask) {
    __shared__ _Float16 a_hi[TS * LDK];   // 16896 B
    __shared__ _Float16 a_lo[TS * LDK];   // 16896 B
    __shared__ float cin_s[HDIM];
    __shared__ float v_s[HDIM];
    __shared__ float att_part[4][TS];

    const int sblk = blockIdx.x;     // 0..255
    const int b    = blockIdx.y;     // 0..31
    const int t    = threadIdx.x;
    const int w    = t >> 6;         // wave 0..3
    const int l    = t & 63;
    const int lane16 = l & 15;
    const int q      = l >> 4;

    cin_s[t] = cin[b * HDIM + t];
    v_s[t]   = V[t];

    // ---- stage context tile [TS][DDIM] fp32 -> fp16 hi/lo in LDS ----
    const float* cbase = context + ((size_t)b * S_LEN + (size_t)sblk * TS) * DDIM;
    #pragma unroll
    for (int i = 0; i < 8; ++i) {
        int f   = i * 256 + t;       // float4 index 0..2047
        int row = f >> 6;            // 64 float4 per row
        int c4  = f & 63;
        f32x4 v = *(const f32x4*)(cbase + row * DDIM + c4 * 4);
        h16x2 h0 = __builtin_amdgcn_cvt_pkrtz(v[0], v[1]);
        h16x2 h1 = __builtin_amdgcn_cvt_pkrtz(v[2], v[3]);
        h16x2 l0 = __builtin_amdgcn_cvt_pkrtz(v[0] - (float)h0[0], v[1] - (float)h0[1]);
        h16x2 l1 = __builtin_amdgcn_cvt_pkrtz(v[2] - (float)h1[0], v[3] - (float)h1[1]);
        h16x4 hi; hi[0] = h0[0]; hi[1] = h0[1]; hi[2] = h1[0]; hi[3] = h1[1];
        h16x4 lo; lo[0] = l0[0]; lo[1] = l0[1]; lo[2] = l1[0]; lo[3] = l1[1];
        *(h16x4*)(a_hi + row * LDK + c4 * 4) = hi;
        *(h16x4*)(a_lo + row * LDK + c4 * 4) = lo;
    }
    __syncthreads();

    // ---- 2-pass split-fp16 MFMA: acc += Ah*W + Al*W ----
    f32x4 acc[2][4];   // [m-tile][n-tile within wave's group]
    #pragma unroll
    for (int mt = 0; mt < 2; ++mt)
        #pragma unroll
        for (int i = 0; i < 4; ++i) acc[mt][i] = (f32x4){0.f, 0.f, 0.f, 0.f};

    const int ntb = w * 4;           // wave's 4 n-tiles: distinct per wave
    #pragma unroll
    for (int ks = 0; ks < 8; ++ks) {
        f16x8 bh[4];
        #pragma unroll
        for (int i = 0; i < 4; ++i) {
            int off = (((ntb + i) * 8 + ks) * 64 + l) * 8;
            bh[i] = *(const f16x8*)(Wf + off);      // coalesced 16B/lane, L2-hot
        }
        f16x8 ah[2], al[2];
        #pragma unroll
        for (int mt = 0; mt < 2; ++mt) {
            int o = (mt * 16 + lane16) * LDK + ks * 32 + q * 8;
            ah[mt] = *(const f16x8*)(a_hi + o);     // ds_read_b128
            al[mt] = *(const f16x8*)(a_lo + o);
        }
        #pragma unroll
        for (int mt = 0; mt < 2; ++mt)
            #pragma unroll
            for (int i = 0; i < 4; ++i) {
                acc[mt][i] = __builtin_amdgcn_mfma_f32_16x16x32_f16(ah[mt], bh[i], acc[mt][i], 0, 0, 0);
                acc[mt][i] = __builtin_amdgcn_mfma_f32_16x16x32_f16(al[mt], bh[i], acc[mt][i], 0, 0, 0);
            }
    }

    // ---- epilogue: tanh(ctx + cin) * V, reduce over h ----
    // C/D layout: col h' = lane&15 (within n-tile), row s' = quad*4 + reg
    float part[2][4] = {};   // [mt][reg]
    #pragma unroll
    for (int i = 0; i < 4; ++i) {
        int h = (ntb + i) * 16 + lane16;
        float c  = cin_s[h];
        float vv = v_s[h];
        #pragma unroll
        for (int mt = 0; mt < 2; ++mt)
            #pragma unroll
            for (int r = 0; r < 4; ++r)
                part[mt][r] += fast_tanh(acc[mt][i][r] + c) * vv;
    }
    // sum the 16 h-columns within each quad (xor 1,2,4,8 stays inside 16 lanes)
    #pragma unroll
    for (int mt = 0; mt < 2; ++mt)
        #pragma unroll
        for (int r = 0; r < 4; ++r) {
            float v = part[mt][r];
            v += __shfl_xor(v, 1);
            v += __shfl_xor(v, 2);
            v += __shfl_xor(v, 4);
            v += __shfl_xor(v, 8);
            part[mt][r] = v;
        }
    if (lane16 == 0) {
        #pragma unroll
        for (int mt = 0; mt < 2; ++mt)
            #pragma unroll
            for (int r = 0; r < 4; ++r)
                att_part[w][mt * 16 + q * 4 + r] = part[mt][r];
    }
    __syncthreads();

    if (t < TS) {
        float a = att_part[0][t] + att_part[1][t] + att_part[2][t] + att_part[3][t];
        a = 10.0f * fast_tanh(a);
        int s  = sblk * TS + t;
        int mk = mask[b * S_LEN + s];
        att[(size_t)b * S_LEN + s] = mk ? a : -INFINITY;
        out_mask[(size_t)b * S_LEN + s] = mk ? 1.0f : 0.0f;
    }
}

// ---------------------------------------------------------------------------
// Kernel 2: per-b argmax (first-index ties, like jnp.argmax) + p = 1/sum(exp)
// out layout: [0,32) indices as float, [32,64) p, [64,...) mask (written above)
// ---------------------------------------------------------------------------
__global__ void reduce_kernel(const float* __restrict__ att,
                              float* __restrict__ out) {
    __shared__ float smax[256];
    __shared__ int   sidx[256];
    const int b = blockIdx.x;
    const int t = threadIdx.x;
    const float* row = att + (size_t)b * S_LEN;

    float best = -INFINITY;
    int   bid  = 0x7fffffff;
    for (int s = t; s < S_LEN; s += 256) {
        float v = row[s];
        if (v > best) { best = v; bid = s; }   // ascending s -> first index within thread
    }
    smax[t] = best; sidx[t] = bid;
    __syncthreads();
    for (int off = 128; off > 0; off >>= 1) {
        if (t < off) {
            float ov = smax[t + off]; int oi = sidx[t + off];
            if (ov > smax[t] || (ov == smax[t] && oi < sidx[t])) { smax[t] = ov; sidx[t] = oi; }
        }
        __syncthreads();
    }
    const float mx = smax[0];
    const int   ix = sidx[0];
    __syncthreads();

    float sum = 0.f;
    for (int s = t; s < S_LEN; s += 256)
        sum += __expf(row[s] - mx);            // masked -inf -> exp -> 0
    smax[t] = sum;
    __syncthreads();
    for (int off = 128; off > 0; off >>= 1) {
        if (t < off) smax[t] += smax[t + off];
        __syncthreads();
    }
    if (t == 0) {
        out[b]         = (float)ix;
        out[BATCH + b] = 1.0f / smax[0];
    }
}

// ---------------------------------------------------------------------------
extern "C" void kernel_launch(void* const* d_in, const int* in_sizes, int n_in,
                              void* d_out, int out_size, void* d_ws, size_t ws_size,
                              hipStream_t stream) {
    const float* x       = (const float*)d_in[0];
    const float* context = (const float*)d_in[1];
    const int*   mask    = (const int*)d_in[2];
    const float* W_in    = (const float*)d_in[3];
    const float* b_in    = (const float*)d_in[4];
    const float* W_ctx   = (const float*)d_in[5];
    const float* b_ctx   = (const float*)d_in[6];
    const float* V       = (const float*)d_in[7];
    float* out = (float*)d_out;

    char* ws = (char*)d_ws;
    float*    cin = (float*)ws;                       // 32 KB
    _Float16* Wf  = (_Float16*)(ws + 32 * 1024);      // 128 KB
    float*    att = (float*)(ws + 160 * 1024);        // 1 MB

    float* out_mask = out + 64;

    prep_kernel<<<64, 256, 0, stream>>>(x, W_in, b_in, W_ctx, b_ctx, cin, Wf);
    dim3 grid(S_LEN / TS, BATCH);
    att_kernel<<<grid, 256, 0, stream>>>(context, mask, cin, V, Wf, att, out_mask);
    reduce_kernel<<<BATCH, 256, 0, stream>>>(att, out);
}

// Round 5
// 418.305 us; speedup vs baseline: 1.1998x; 1.0389x over previous
//
#include <hip/hip_runtime.h>
#include <math.h>

#define S_LEN 8192
#define BATCH 32
#define HDIM 256
#define DDIM 256
#define SCHUNK 512      // s-rows per block
#define NSUB 8          // subtiles per block
#define TSUB 64         // s-rows per subtile
#define LDK 264         // padded LDS row stride (halfs): 528 B rows

typedef float f32x4 __attribute__((ext_vector_type(4)));
typedef __fp16 h16x2 __attribute__((ext_vector_type(2)));
typedef __fp16 h16x4 __attribute__((ext_vector_type(4)));
typedef _Float16 f16x8 __attribute__((ext_vector_type(8)));

static __device__ __forceinline__ float fast_tanh(float x) {
    // 1 - 2/(exp(2x)+1); monotone, NaN-free, saturates correctly at +-inf
    float e = __expf(2.0f * x);
    return 1.0f - 2.0f / (e + 1.0f);
}

// fp32x4 -> fp16 hi (RTZ) + fp16 lo residual, stored as 8B each
static __device__ __forceinline__ void cvt_store(f32x4 v, _Float16* ph, _Float16* pl) {
    h16x2 h0 = __builtin_amdgcn_cvt_pkrtz(v[0], v[1]);
    h16x2 h1 = __builtin_amdgcn_cvt_pkrtz(v[2], v[3]);
    h16x2 l0 = __builtin_amdgcn_cvt_pkrtz(v[0] - (float)h0[0], v[1] - (float)h0[1]);
    h16x2 l1 = __builtin_amdgcn_cvt_pkrtz(v[2] - (float)h1[0], v[3] - (float)h1[1]);
    h16x4 hi; hi[0] = h0[0]; hi[1] = h0[1]; hi[2] = h1[0]; hi[3] = h1[1];
    h16x4 lo; lo[0] = l0[0]; lo[1] = l0[1]; lo[2] = l1[0]; lo[3] = l1[1];
    *(h16x4*)ph = hi;
    *(h16x4*)pl = lo;
}

// ---------------------------------------------------------------------------
// Kernel 0: blocks [0,32): cin[b][h] = x[b]·W_in[h] + b_in[h] + b_ctx[h]
//           blocks [32,64): W_ctx -> fp16 (RNE), swizzled into MFMA A-frag
//           order: Wf[((ht*8+ks)*64 + lane)*8 + j] =
//              fp16(W_ctx[h = ht*16 + (lane&15)][d = ks*32 + (lane>>4)*8 + j])
// ---------------------------------------------------------------------------
__global__ void prep_kernel(const float* __restrict__ x,
                            const float* __restrict__ W_in,
                            const float* __restrict__ b_in,
                            const float* __restrict__ W_ctx,
                            const float* __restrict__ b_ctx,
                            float* __restrict__ cin,
                            _Float16* __restrict__ Wf) {
    __shared__ float xs[DDIM];
    const int bx = blockIdx.x;
    const int t  = threadIdx.x;
    if (bx < BATCH) {
        xs[t] = x[bx * DDIM + t];
        __syncthreads();
        const float* wr = W_in + t * DDIM;   // thread t owns output h = t
        float acc = b_in[t] + b_ctx[t];
        #pragma unroll 8
        for (int d = 0; d < DDIM; ++d) acc += xs[d] * wr[d];
        cin[bx * HDIM + t] = acc;
    } else {
        const int g  = (bx - BATCH) * 256 + t;   // 0..8191 fragment-groups
        const int ht = g >> 9;
        const int ks = (g >> 6) & 7;
        const int l  = g & 63;
        const int h  = ht * 16 + (l & 15);
        const int d0 = ks * 32 + (l >> 4) * 8;
        const float* src = W_ctx + h * DDIM + d0;
        f16x8 vh;
        #pragma unroll
        for (int j = 0; j < 8; ++j) vh[j] = (_Float16)src[j];   // v_cvt_f16_f32, RNE
        *(f16x8*)(Wf + (size_t)g * 8) = vh;
    }
}

// ---------------------------------------------------------------------------
// Kernel 1: C[h][s] = W·ctx^T. W A-frags register-resident per wave (h-tile=w);
// context staged fp32->fp16 hi/lo in double-buffered LDS as B operand.
// acc = W*(ctx_hi) + W*(ctx_lo) = exact fp16(W)·ctx to ~2^-22.
// Epilogue: per-s reduce over h of tanh(.+cin[h])*V[h] -> att, out_mask.
// ---------------------------------------------------------------------------
__launch_bounds__(1024, 4)
__global__ void att_kernel(const float* __restrict__ context,
                           const int* __restrict__ mask,
                           const float* __restrict__ cin,
                           const float* __restrict__ V,
                           const _Float16* __restrict__ Wf,
                           float* __restrict__ att,
                           float* __restrict__ out_mask) {
    __shared__ __align__(16) _Float16 a_hi[2][TSUB * LDK];   // 2 x 33792 B
    __shared__ __align__(16) _Float16 a_lo[2][TSUB * LDK];   // 2 x 33792 B
    __shared__ float att_part[2][16][TSUB];                  // 8 KB

    const int schunk = blockIdx.x;   // 0..15
    const int b      = blockIdx.y;   // 0..31
    const int t      = threadIdx.x;  // 0..1023
    const int w      = t >> 6;       // wave 0..15 -> h-tile w (h in [w*16, w*16+16))
    const int l      = t & 63;
    const int lane16 = l & 15;
    const int q      = l >> 4;

    // W A-fragments, register-resident for the whole kernel (32 VGPRs)
    f16x8 wfrag[8];
    #pragma unroll
    for (int ks = 0; ks < 8; ++ks)
        wfrag[ks] = *(const f16x8*)(Wf + (size_t)((w * 8 + ks) * 64 + l) * 8);

    // per-lane cin/V for epilogue rows: h = w*16 + q*4 + r
    float cinr[4], vr[4];
    #pragma unroll
    for (int r = 0; r < 4; ++r) {
        int h = w * 16 + q * 4 + r;
        cinr[r] = cin[b * HDIM + h];
        vr[r]   = V[h];
    }

    const float* cbase = context + ((size_t)b * S_LEN + (size_t)schunk * SCHUNK) * DDIM;

    // ---- stage subtile 0 into buf 0 ----
    #pragma unroll
    for (int i = 0; i < 4; ++i) {
        int f = i * 1024 + t, row = f >> 6, c4 = f & 63;
        f32x4 v = *(const f32x4*)(cbase + row * DDIM + c4 * 4);   // coalesced 16B/lane
        cvt_store(v, &a_hi[0][row * LDK + c4 * 4], &a_lo[0][row * LDK + c4 * 4]);
    }
    __syncthreads();

    for (int it = 0; it < NSUB; ++it) {
        const int cur = it & 1;
        const bool pre = (it + 1 < NSUB);

        // issue next subtile's global loads early (hidden under MFMA)
        f32x4 pf[4];
        if (pre) {
            const float* nb = cbase + (size_t)(it + 1) * TSUB * DDIM;
            #pragma unroll
            for (int i = 0; i < 4; ++i) {
                int f = i * 1024 + t, row = f >> 6, c4 = f & 63;
                pf[i] = *(const f32x4*)(nb + row * DDIM + c4 * 4);
            }
        }

        // ---- MFMA: acc[nt] (16 h x 16 s per tile), 2-pass hi/lo ----
        f32x4 acc[4];
        #pragma unroll
        for (int nt = 0; nt < 4; ++nt) acc[nt] = (f32x4){0.f, 0.f, 0.f, 0.f};
        #pragma unroll
        for (int ks = 0; ks < 8; ++ks) {
            #pragma unroll
            for (int nt = 0; nt < 4; ++nt) {
                int o = (nt * 16 + lane16) * LDK + ks * 32 + q * 8;
                f16x8 bh = *(const f16x8*)(&a_hi[cur][o]);   // ds_read_b128
                f16x8 bl = *(const f16x8*)(&a_lo[cur][o]);
                acc[nt] = __builtin_amdgcn_mfma_f32_16x16x32_f16(wfrag[ks], bh, acc[nt], 0, 0, 0);
                acc[nt] = __builtin_amdgcn_mfma_f32_16x16x32_f16(wfrag[ks], bl, acc[nt], 0, 0, 0);
            }
        }

        // ---- epilogue: C/D row = h (quad*4+reg), col = s (lane16) ----
        #pragma unroll
        for (int nt = 0; nt < 4; ++nt) {
            float p = 0.f;
            #pragma unroll
            for (int r = 0; r < 4; ++r)
                p += fast_tanh(acc[nt][r] + cinr[r]) * vr[r];
            p += __shfl_xor(p, 16);     // reduce over quads (h groups)
            p += __shfl_xor(p, 32);
            if (l < 16) att_part[cur][w][nt * 16 + l] = p;
        }

        // ---- convert + store next subtile into buf cur^1 ----
        if (pre) {
            #pragma unroll
            for (int i = 0; i < 4; ++i) {
                int f = i * 1024 + t, row = f >> 6, c4 = f & 63;
                cvt_store(pf[i], &a_hi[cur ^ 1][row * LDK + c4 * 4],
                                 &a_lo[cur ^ 1][row * LDK + c4 * 4]);
            }
        }
        __syncthreads();

        // ---- finalize this subtile's 64 s-values ----
        if (t < TSUB) {
            float a = 0.f;
            #pragma unroll
            for (int ww = 0; ww < 16; ++ww) a += att_part[cur][ww][t];
            a = 10.0f * fast_tanh(a);
            int s  = schunk * SCHUNK + it * TSUB + t;
            int mk = mask[b * S_LEN + s];
            att[(size_t)b * S_LEN + s]      = mk ? a : -INFINITY;
            out_mask[(size_t)b * S_LEN + s] = mk ? 1.0f : 0.0f;
        }
    }
}

// ---------------------------------------------------------------------------
// Kernel 2: per-b argmax (first-index ties, like jnp.argmax) + p = 1/sum(exp)
// out layout: [0,32) indices as float, [32,64) p, [64,...) mask (written above)
// ---------------------------------------------------------------------------
__global__ void reduce_kernel(const float* __restrict__ att,
                              float* __restrict__ out) {
    __shared__ float smax[256];
    __shared__ int   sidx[256];
    const int b = blockIdx.x;
    const int t = threadIdx.x;
    const float* row = att + (size_t)b * S_LEN;

    float best = -INFINITY;
    int   bid  = 0x7fffffff;
    for (int s = t; s < S_LEN; s += 256) {
        float v = row[s];
        if (v > best) { best = v; bid = s; }   // ascending s -> first index within thread
    }
    smax[t] = best; sidx[t] = bid;
    __syncthreads();
    for (int off = 128; off > 0; off >>= 1) {
        if (t < off) {
            float ov = smax[t + off]; int oi = sidx[t + off];
            if (ov > smax[t] || (ov == smax[t] && oi < sidx[t])) { smax[t] = ov; sidx[t] = oi; }
        }
        __syncthreads();
    }
    const float mx = smax[0];
    const int   ix = sidx[0];
    __syncthreads();

    float sum = 0.f;
    for (int s = t; s < S_LEN; s += 256)
        sum += __expf(row[s] - mx);            // masked -inf -> exp -> 0
    smax[t] = sum;
    __syncthreads();
    for (int off = 128; off > 0; off >>= 1) {
        if (t < off) smax[t] += smax[t + off];
        __syncthreads();
    }
    if (t == 0) {
        out[b]         = (float)ix;
        out[BATCH + b] = 1.0f / smax[0];
    }
}

// ---------------------------------------------------------------------------
extern "C" void kernel_launch(void* const* d_in, const int* in_sizes, int n_in,
                              void* d_out, int out_size, void* d_ws, size_t ws_size,
                              hipStream_t stream) {
    const float* x       = (const float*)d_in[0];
    const float* context = (const float*)d_in[1];
    const int*   mask    = (const int*)d_in[2];
    const float* W_in    = (const float*)d_in[3];
    const float* b_in    = (const float*)d_in[4];
    const float* W_ctx   = (const float*)d_in[5];
    const float* b_ctx   = (const float*)d_in[6];
    const float* V       = (const float*)d_in[7];
    float* out = (float*)d_out;

    char* ws = (char*)d_ws;
    float*    cin = (float*)ws;                       // 32 KB
    _Float16* Wf  = (_Float16*)(ws + 32 * 1024);      // 128 KB
    float*    att = (float*)(ws + 160 * 1024);        // 1 MB

    float* out_mask = out + 64;

    prep_kernel<<<64, 256, 0, stream>>>(x, W_in, b_in, W_ctx, b_ctx, cin, Wf);
    dim3 grid(S_LEN / SCHUNK, BATCH);                 // 16 x 32 = 512 blocks
    att_kernel<<<grid, 1024, 0, stream>>>(context, mask, cin, V, Wf, att, out_mask);
    reduce_kernel<<<BATCH, 256, 0, stream>>>(att, out);
}